// Round 10
// baseline (1629.838 us; speedup 1.0000x reference)
//
#include <hip/hip_runtime.h>

typedef unsigned short u16;
typedef unsigned int   u32;
typedef __attribute__((ext_vector_type(8))) short bf16x8;
typedef __attribute__((ext_vector_type(4))) float f32x4;

#define DI __device__ __forceinline__

DI float b2f(u16 u){ union{u32 i; float f;} x; x.i = ((u32)u)<<16; return x.f; }
DI u16 f2bf(float f){ union{float f; u32 i;} x; x.f=f; u32 r = x.i + 0x7FFFu + ((x.i>>16)&1u); return (u16)(r>>16); }
DI float sigf(float x){ return 1.0f/(1.0f + __expf(-x)); }
DI float tanh_(float x){ return 1.0f - 2.0f/(__expf(2.0f*x)+1.0f); }
DI float dot4(float4 a, float4 b){ return a.x*b.x + a.y*b.y + a.z*b.z + a.w*b.w; }

// ---------------- conv1 (k=7,pad3) + BN1 + ReLU + maxpool2 ----------------
// x: [128][2048][8] f32  -> out: [128][128][1024] bf16  (layout [b][co][t'])
__global__ __launch_bounds__(256) void k_conv1(
    const float* __restrict__ x, const float* __restrict__ w,
    const float* __restrict__ cb, const float* __restrict__ bg, const float* __restrict__ bb,
    const float* __restrict__ bm, const float* __restrict__ bv, u16* __restrict__ out)
{
  __shared__ __align__(16) float xs[262*12];    // [tau+3][8ci pad12]
  __shared__ __align__(16) float wl[128*7*8];   // [co][k][ci]
  __shared__ float As[128], Ss[128];
  const int tid = threadIdx.x;
  const int tc  = blockIdx.x;       // 8 chunks of 128 pooled positions
  const int b   = blockIdx.y;
  const int tau0 = tc*256;
  for(int f = tid; f < 262*8; f += 256){
    int tt = f >> 3;
    int ci = f & 7;
    int xg = tau0 - 3 + tt;
    float val = 0.f;
    if(xg >= 0 && xg < 2048) val = x[(b*2048 + xg)*8 + ci];
    xs[tt*12 + ci] = val;
  }
  for(int d = tid; d < 128*7*8; d += 256){
    int co = d / 56; int r = d - co*56; int k = r >> 3; int ci = r & 7;
    wl[d] = w[(co*8 + ci)*7 + k];
  }
  if(tid < 128){
    float a = bg[tid] * rsqrtf(bv[tid] + 1e-5f);
    As[tid] = a;
    Ss[tid] = (cb[tid] - bm[tid])*a + bb[tid];
  }
  __syncthreads();
  const float4* xs4 = (const float4*)xs;
  const float4* wl4 = (const float4*)wl;
  const int p2  = tid & 63;         // pooled pair index (p = 2*p2, 2*p2+1)
  const int grp = tid >> 6;         // co group (wave-uniform)
  float4 ra[10], rb[10];
  #pragma unroll
  for(int e=0; e<10; e++){ ra[e] = xs4[(4*p2+e)*3]; rb[e] = xs4[(4*p2+e)*3 + 1]; }
  u32* out32 = (u32*)out;
  for(int i = 0; i < 32; i++){
    const int co = grp*32 + i;
    float a0=0.f, a1=0.f, a2=0.f, a3=0.f;
    #pragma unroll
    for(int k=0;k<7;k++){
      float4 wa = wl4[(co*7+k)*2], wb2 = wl4[(co*7+k)*2+1];
      a0 += dot4(ra[k],   wa) + dot4(rb[k],   wb2);
      a1 += dot4(ra[k+1], wa) + dot4(rb[k+1], wb2);
      a2 += dot4(ra[k+2], wa) + dot4(rb[k+2], wb2);
      a3 += dot4(ra[k+3], wa) + dot4(rb[k+3], wb2);
    }
    const float Ac = As[co], Sc = Ss[co];
    const float y0 = fmaxf(fmaxf(a0*Ac+Sc, a1*Ac+Sc), 0.f);
    const float y1 = fmaxf(fmaxf(a2*Ac+Sc, a3*Ac+Sc), 0.f);
    out32[((b*128 + co)<<9) + tc*64 + p2] = (u32)f2bf(y0) | ((u32)f2bf(y1) << 16);
  }
}

// ---------------- FUSED conv2+BN+pool  ->  xp = LN(seq @ wih.T + bih) ------
// Phase A: R8 k_conv2 verbatim (3-way W split computed on the fly, identical
// ops to k_prep). Epilogue writes the 128x256 seq tile to LDS (pitch 264)
// instead of HBM. Phase B: R8 k_xp verbatim per dir with A-fragments from the
// LDS seq tile; LN epilogue staged via a 2-half [64][392] ost overlaying the
// dead W-staging region. seq never touches HBM. All op orders preserved.
// Block: (tc 0..3, b) -> xp rows (tc*128 + 0..127)*128 + b. 512 thr, 8 waves.
__global__ __launch_bounds__(512) void k_c2xp(
    const u16* __restrict__ cin, const float* __restrict__ w2,
    const float* __restrict__ cb, const float* __restrict__ bg, const float* __restrict__ bb,
    const float* __restrict__ bm, const float* __restrict__ bv,
    const float* __restrict__ fw, const float* __restrict__ fbi, const float* __restrict__ fg, const float* __restrict__ fb,
    const float* __restrict__ bw, const float* __restrict__ bbi, const float* __restrict__ bg_, const float* __restrict__ bb_,
    u16* __restrict__ xpf, u16* __restrict__ xpb)
{
  // LDS overlays (138816 B total):
  //  [0,70720)        phase A: xsT[260][136] u16 | phase B: seqL[128][264] u16
  //  [70720,132160)   phase A: wb0/wb1/wb2 [256*40]u16 | phase B: wbh/wbl
  //                   [384*40]u16 | epilogue: ost[64][392] u16
  //  [132160,134208)  As[256], Ss[256] f32          (phase A only)
  //  [134208,138816)  lnbi/lng/lnb2 [384] f32 each  (phase B only)
  __shared__ __align__(16) char lds[138816];
  u16*   xsT  = (u16*)lds;
  u16*   wb0  = (u16*)(lds + 70720);
  u16*   wb1  = (u16*)(lds + 91200);
  u16*   wb2s = (u16*)(lds + 111680);
  float* As   = (float*)(lds + 132160);
  float* Ss   = (float*)(lds + 133184);
  u16*   seqL = (u16*)lds;
  u16*   wbh  = (u16*)(lds + 70720);
  u16*   wbl  = (u16*)(lds + 101440);
  u16*   ost  = (u16*)(lds + 70720);
  float* lnbi = (float*)(lds + 134208);
  float* lng  = lnbi + 384;
  float* lnb2 = lnbi + 768;
  const int tid = threadIdx.x;
  const int tc  = blockIdx.x;    // 0..3 (256 tau each)
  const int b   = blockIdx.y;
  const int wav = tid >> 6;
  const int rt  = wav & 3;       // base tau-tile
  const int coh = wav >> 2;      // co half (128)
  const int l = tid & 63;
  const int g = l >> 4;          // k-group 0..3
  const int c = l & 15;
  // ======================= PHASE A: conv2 =======================
  if(tid < 256){
    float a = bg[tid] * rsqrtf(bv[tid] + 1e-5f);
    As[tid] = a; Ss[tid] = (cb[tid] - bm[tid])*a + bb[tid];
  }
  // stage X^T: tt = 0..259 <-> tg = tc*256 - 2 + tt
  for(int f = tid; f < 33280; f += 512){
    int ci = f / 260, tt = f - ci*260;
    int tg = tc*256 - 2 + tt;
    u16 val = 0;
    if(tg >= 0 && tg < 1024) val = cin[((b*128 + ci)<<10) + tg];
    xsT[tt*136 + ci] = val;
  }
  f32x4 acc[4][8];
  #pragma unroll
  for(int q4=0;q4<4;q4++)
    #pragma unroll
    for(int n=0;n<8;n++) acc[q4][n] = (f32x4){0.f,0.f,0.f,0.f};
  for(int s=0; s<20; s++){
    const int k = s >> 2, cib = s & 3;
    __syncthreads();                 // prev MFMA reads done; (iter0: xsT/As ready)
    for(int f = tid; f < 8192; f += 512){
      int co = f >> 5, cl = f & 31;
      float wvv = w2[co*640 + (cib*32 + cl)*5 + k];
      u16 h0 = f2bf(wvv);
      float r1 = wvv - b2f(h0);      // exact in f32
      u16 h1 = f2bf(r1);
      float r2 = r1 - b2f(h1);       // exact in f32
      wb0[co*40 + cl] = h0;
      wb1[co*40 + cl] = h1;
      wb2s[co*40 + cl] = f2bf(r2);
    }
    __syncthreads();                 // wb visible
    bf16x8 afr2[4];
    #pragma unroll
    for(int q4=0;q4<4;q4++)
      afr2[q4] = *(const bf16x8*)&xsT[((q4*4 + rt)*16 + c + k)*136 + cib*32 + g*8];
    #pragma unroll
    for(int n=0; n<8; n++){
      bf16x8 b0 = *(const bf16x8*)&wb0[(coh*128 + n*16 + c)*40 + g*8];
      bf16x8 b1 = *(const bf16x8*)&wb1[(coh*128 + n*16 + c)*40 + g*8];
      bf16x8 b2 = *(const bf16x8*)&wb2s[(coh*128 + n*16 + c)*40 + g*8];
      #pragma unroll
      for(int q4=0;q4<4;q4++){
        acc[q4][n] = __builtin_amdgcn_mfma_f32_16x16x32_bf16(afr2[q4], b0, acc[q4][n], 0, 0, 0);
        acc[q4][n] = __builtin_amdgcn_mfma_f32_16x16x32_bf16(afr2[q4], b1, acc[q4][n], 0, 0, 0);
        acc[q4][n] = __builtin_amdgcn_mfma_f32_16x16x32_bf16(afr2[q4], b2, acc[q4][n], 0, 0, 0);
      }
    }
  }
  __syncthreads();                   // all xsT/wb reads done -> safe to overwrite
  // epilogue: BN + ReLU + maxpool2 -> seqL[tp_local][co], pitch 264
  #pragma unroll
  for(int q4=0;q4<4;q4++){
    const int T = q4*4 + rt;
    const int tpl = T*8 + g*2;
    #pragma unroll
    for(int n=0; n<8; n++){
      int co = coh*128 + n*16 + c;
      float Ac = As[co], Sc = Ss[co];
      float p0 = fmaxf(fmaxf(acc[q4][n][0]*Ac+Sc, acc[q4][n][1]*Ac+Sc), 0.f);
      float p1 = fmaxf(fmaxf(acc[q4][n][2]*Ac+Sc, acc[q4][n][3]*Ac+Sc), 0.f);
      seqL[(tpl+0)*264 + co] = f2bf(p0);
      seqL[(tpl+1)*264 + co] = f2bf(p1);
    }
  }
  __syncthreads();                   // seqL visible
  // ======================= PHASE B: xp (both dirs) =======================
  bf16x8 afr[8];
  #pragma unroll
  for(int ks=0; ks<8; ks++)
    afr[ks] = *(const bf16x8*)&seqL[(wav*16 + c)*264 + ks*32 + g*8];
  for(int d=0; d<2; d++){
    const float *W  = d ? bw  : fw;
    const float *BI = d ? bbi : fbi;
    const float *LG = d ? bg_ : fg;
    const float *LB = d ? bb_ : fb;
    u16* outp = d ? xpb : xpf;
    __syncthreads();                 // afr reads / prev-dir ost copies done
    if(tid < 384){ lnbi[tid] = BI[tid]; lng[tid] = LG[tid]; lnb2[tid] = LB[tid]; }
    f32x4 axc[24];
    #pragma unroll
    for(int n=0; n<24; n++) axc[n] = (f32x4){0.f,0.f,0.f,0.f};
    for(int ks=0; ks<8; ks++){
      if(ks) __syncthreads();        // prev-step MFMA reads done
      for(int f = tid; f < 12288; f += 512){
        int jj = f >> 5, kk = f & 31;
        float wvv = W[jj*256 + ks*32 + kk];
        u16 hi = f2bf(wvv);
        wbh[jj*40 + kk] = hi;
        wbl[jj*40 + kk] = f2bf(wvv - b2f(hi));
      }
      __syncthreads();               // W staging visible
      #pragma unroll
      for(int n=0; n<24; n++){
        bf16x8 bhi = *(const bf16x8*)&wbh[(n*16 + c)*40 + g*8];
        bf16x8 blo = *(const bf16x8*)&wbl[(n*16 + c)*40 + g*8];
        axc[n] = __builtin_amdgcn_mfma_f32_16x16x32_bf16(afr[ks], bhi, axc[n], 0, 0, 0);
        axc[n] = __builtin_amdgcn_mfma_f32_16x16x32_bf16(afr[ks], blo, axc[n], 0, 0, 0);
      }
    }
    // LN epilogue (same op order as k_xp)
    float bic[24];
    #pragma unroll
    for(int n=0; n<24; n++) bic[n] = lnbi[n*16 + c];
    float mean[4], rs[4];
    #pragma unroll
    for(int q=0; q<4; q++){
      float s = 0.f, ss = 0.f;
      #pragma unroll
      for(int n=0; n<24; n++){
        float u = axc[n][q] + bic[n];
        s += u; ss += u*u;
      }
      #pragma unroll
      for(int msk=1; msk<16; msk<<=1){ s += __shfl_xor(s,msk); ss += __shfl_xor(ss,msk); }
      mean[q] = s * (1.f/384.f);
      float var = fmaxf(ss * (1.f/384.f) - mean[q]*mean[q], 0.f);
      rs[q] = rsqrtf(var + 1e-5f);
    }
    // two-half ost staging (ost overlays dead W staging) + coalesced store
    for(int h=0; h<2; h++){
      __syncthreads();               // MFMA/W reads (h=0) or prior copies (h=1) done
      if((wav >> 2) == h){
        #pragma unroll
        for(int n=0; n<24; n++){
          float lgv = lng[n*16 + c], lbv = lnb2[n*16 + c];
          #pragma unroll
          for(int q=0; q<4; q++){
            float u = axc[n][q] + bic[n];
            float y = (u - mean[q])*rs[q]*lgv + lbv;
            ost[((wav&3)*16 + g*4 + q)*392 + n*16 + c] = f2bf(y);
          }
        }
      }
      __syncthreads();               // ost half visible
      for(int f2 = tid; f2 < 3072; f2 += 512){
        int r64 = f2 / 48, ch = f2 - r64*48;
        int grow = (tc*128 + h*64 + r64)*128 + b;  // xp row = tp*128 + b
        uint4 v = *(const uint4*)&ost[r64*392 + ch*8];
        *(uint4*)&outp[grow*384 + ch*8] = v;
      }
    }
  }
}

// ---------------- LayerNorm-LSTM scan (one block per (batch,dir)) ----------------
// R0 structure (validated local optimum across 5 restructure attempts) +
// batched hcat stores + xt prefetch (neutral but harmless).
__global__ __launch_bounds__(384) void k_lstm(
    const u16* __restrict__ xpf, const u16* __restrict__ xpb,
    const float* __restrict__ fwhh, const float* __restrict__ fbhh, const float* __restrict__ fgh, const float* __restrict__ fbh2,
    const float* __restrict__ fgho, const float* __restrict__ fbho,
    const float* __restrict__ bwhh, const float* __restrict__ bbhh, const float* __restrict__ bgh, const float* __restrict__ bbh2,
    const float* __restrict__ bgho, const float* __restrict__ bbho,
    u16* __restrict__ hcat)
{
  __shared__ float4 hx4[24];
  __shared__ float gbuf[384];
  __shared__ float red[16];
  __shared__ __align__(16) u16 hstage[8][96];   // 8 steps of hy
  const int b   = blockIdx.x;
  const int dir = blockIdx.y;
  const u16* xp;
  const float *whh, *bh, *gh, *bh2, *gho, *bho;
  if(dir == 0){ xp=xpf; whh=fwhh; bh=fbhh; gh=fgh; bh2=fbh2; gho=fgho; bho=fbho; }
  else        { xp=xpb; whh=bwhh; bh=bbhh; gh=bgh; bh2=bbh2; gho=bgho; bho=bbho; }
  const int j = threadIdx.x;
  const int wid = j >> 6;
  float wr[96];                         // whh row j in registers
  {
    const float4* wp4 = (const float4*)(whh + j*96);
    #pragma unroll
    for(int kk=0; kk<24; kk++){
      float4 v = wp4[kk];
      wr[4*kk]=v.x; wr[4*kk+1]=v.y; wr[4*kk+2]=v.z; wr[4*kk+3]=v.w;
    }
  }
  const float bh_j = bh[j], gh_j = gh[j], bh2_j = bh2[j];
  float gho_j = 0.f, bho_j = 0.f, cx = 0.f;
  if(j < 96){ gho_j = gho[j]; bho_j = bho[j]; }
  float* hx = (float*)hx4;
  if(j < 96) hx[j] = 0.f;
  const u16* xrow = xp + b*384 + j;      // + ts*49152 per step
  u16 xt_u = xrow[(dir ? 511 : 0)*49152];
  __syncthreads();
  for(int t=0; t<512; t++){
    const int ts = dir ? (511 - t) : t;
    u16 xn = 0;
    if(t < 511) xn = xrow[(dir ? (510 - t) : (t + 1))*49152];
    const float xt = b2f(xt_u);
    float a0=0.f,a1=0.f,a2=0.f,a3=0.f;
    #pragma unroll
    for(int kk=0; kk<24; kk++){
      float4 h4 = hx4[kk];              // broadcast read
      a0 += h4.x * wr[4*kk];
      a1 += h4.y * wr[4*kk+1];
      a2 += h4.z * wr[4*kk+2];
      a3 += h4.w * wr[4*kk+3];
    }
    const float u = (a0+a1)+(a2+a3) + bh_j;
    float s = u, ss = u*u;
    #pragma unroll
    for(int msk=32; msk; msk>>=1){ s += __shfl_xor(s,msk); ss += __shfl_xor(ss,msk); }
    if((j & 63) == 0){ red[wid*2] = s; red[wid*2+1] = ss; }
    __syncthreads();
    float S=0.f, SS=0.f;
    #pragma unroll
    for(int wv=0; wv<6; wv++){ S += red[wv*2]; SS += red[wv*2+1]; }
    const float mean = S*(1.f/384.f);
    const float var  = fmaxf(SS*(1.f/384.f) - mean*mean, 0.f);
    const float rs   = rsqrtf(var + 1e-5f);
    const float gate = xt + (u - mean)*rs*gh_j + bh2_j;
    gbuf[j] = gate;
    __syncthreads();
    float cy = 0.f, go_ = 0.f;
    if(j < 128){
      if(j < 96){
        float gi = gbuf[j], gf = gbuf[j+96], gg = gbuf[j+192];
        go_ = gbuf[j+288];
        cy = sigf(gf)*cx + sigf(gi)*tanh_(gg);
        cx = cy;
      }
      float s2 = cy, ss2 = cy*cy;
      #pragma unroll
      for(int msk=32; msk; msk>>=1){ s2 += __shfl_xor(s2,msk); ss2 += __shfl_xor(ss2,msk); }
      if((j & 63) == 0){ red[12 + wid*2] = s2; red[13 + wid*2] = ss2; }
    }
    __syncthreads();
    if(j < 96){
      const float S2 = red[12]+red[14], SS2 = red[13]+red[15];
      const float m2  = S2*(1.f/96.f);
      const float v2  = fmaxf(SS2*(1.f/96.f) - m2*m2, 0.f);
      const float rs2 = rsqrtf(v2 + 1e-5f);
      const float lnho = (cy - m2)*rs2*gho_j + bho_j;
      const float hy = sigf(go_)*tanh_(lnho);
      hx[j] = hy;
      hstage[t & 7][j] = f2bf(hy);
    }
    xt_u = xn;
    __syncthreads();
    if((t & 7) == 7){
      if(j < 96){
        const int row = j / 12, ch = j - row*12;
        const int tt = (t - 7) + row;
        const int tsr = dir ? (511 - tt) : tt;
        uint4 v = *(const uint4*)&hstage[row][ch*8];
        *(uint4*)&hcat[(tsr*128 + b)*192 + dir*96 + ch*8] = v;
      }
    }
  }
}

// ---------------- attention + fc1/BN3/ReLU + fc2 (one block per batch) ----------------
__global__ __launch_bounds__(256) void k_head(
    const u16* __restrict__ hcat, const float* __restrict__ aw,
    const float* __restrict__ f1w, const float* __restrict__ f1b,
    const float* __restrict__ g3, const float* __restrict__ b3, const float* __restrict__ m3, const float* __restrict__ v3,
    const float* __restrict__ fc2w, const float* __restrict__ fc2bias,
    float* __restrict__ out)
{
  __shared__ float p[512];
  __shared__ float red[8];
  __shared__ __align__(16) float ctx[192];
  __shared__ float h2[256];
  __shared__ float awl[192];
  const int b = blockIdx.x;
  const int tid = threadIdx.x;
  if(tid < 192) awl[tid] = aw[tid];
  __syncthreads();
  float sc0 = 0.f, sc1 = 0.f;
  #pragma unroll
  for(int i=0;i<2;i++){
    int t = i*256 + tid;
    const uint4* hp = (const uint4*)(hcat + (t*128 + b)*192);
    float acc = 0.f;
    #pragma unroll 6
    for(int qq=0;qq<24;qq++){
      uint4 pv = hp[qq];
      acc += b2f((u16)(pv.x&0xffffu))*awl[qq*8+0] + b2f((u16)(pv.x>>16))*awl[qq*8+1]
           + b2f((u16)(pv.y&0xffffu))*awl[qq*8+2] + b2f((u16)(pv.y>>16))*awl[qq*8+3]
           + b2f((u16)(pv.z&0xffffu))*awl[qq*8+4] + b2f((u16)(pv.z>>16))*awl[qq*8+5]
           + b2f((u16)(pv.w&0xffffu))*awl[qq*8+6] + b2f((u16)(pv.w>>16))*awl[qq*8+7];
    }
    if(i==0) sc0 = acc; else sc1 = acc;
  }
  float mx = fmaxf(sc0, sc1);
  for(int msk=32; msk; msk>>=1) mx = fmaxf(mx, __shfl_xor(mx,msk));
  if((tid&63)==0) red[tid>>6] = mx;
  __syncthreads();
  mx = fmaxf(fmaxf(red[0],red[1]), fmaxf(red[2],red[3]));
  float e0 = __expf(sc0-mx), e1 = __expf(sc1-mx);
  float sm = e0 + e1;
  for(int msk=32; msk; msk>>=1) sm += __shfl_xor(sm,msk);
  if((tid&63)==0) red[4 + (tid>>6)] = sm;
  __syncthreads();
  const float inv = 1.f/(red[4]+red[5]+red[6]+red[7]);
  p[tid] = e0*inv; p[tid+256] = e1*inv;
  __syncthreads();
  if(tid < 192){
    float acc = 0.f;
    for(int t=0;t<512;t++){
      acc += p[t] * b2f(hcat[(t*128 + b)*192 + tid]);
    }
    ctx[tid] = acc;
  }
  __syncthreads();
  {
    const float4* cv = (const float4*)ctx;
    const float4* wp = (const float4*)(f1w + tid*192);
    float acc = 0.f;
    #pragma unroll 8
    for(int qq=0;qq<48;qq++){
      acc += dot4(wp[qq], cv[qq]);
    }
    acc += f1b[tid];
    float a = g3[tid] * rsqrtf(v3[tid] + 1e-5f);
    float y = (acc - m3[tid])*a + b3[tid];
    h2[tid] = fmaxf(y, 0.f);
  }
  __syncthreads();
  if(tid < 6){
    float acc = fc2bias[tid];
    for(int k=0;k<256;k++) acc += h2[k]*fc2w[tid*256 + k];
    out[b*6 + tid] = acc;
  }
}

extern "C" void kernel_launch(void* const* d_in, const int* in_sizes, int n_in,
                              void* d_out, int out_size, void* d_ws, size_t ws_size,
                              hipStream_t stream)
{
  (void)in_sizes; (void)n_in; (void)out_size; (void)ws_size;
  const float* X      = (const float*)d_in[0];
  const float* c1w    = (const float*)d_in[1];
  const float* c1b    = (const float*)d_in[2];
  const float* bn1g   = (const float*)d_in[3];
  const float* bn1b   = (const float*)d_in[4];
  const float* bn1m   = (const float*)d_in[5];
  const float* bn1v   = (const float*)d_in[6];
  const float* c2w    = (const float*)d_in[7];
  const float* c2b    = (const float*)d_in[8];
  const float* bn2g   = (const float*)d_in[9];
  const float* bn2b   = (const float*)d_in[10];
  const float* bn2m   = (const float*)d_in[11];
  const float* bn2v   = (const float*)d_in[12];
  const float* fwih   = (const float*)d_in[13];
  const float* fbih   = (const float*)d_in[14];
  const float* fwhh   = (const float*)d_in[15];
  const float* fbhh   = (const float*)d_in[16];
  const float* flnihg = (const float*)d_in[17];
  const float* flnihb = (const float*)d_in[18];
  const float* flnhhg = (const float*)d_in[19];
  const float* flnhhb = (const float*)d_in[20];
  const float* flnhog = (const float*)d_in[21];
  const float* flnhob = (const float*)d_in[22];
  const float* bwih   = (const float*)d_in[23];
  const float* bbih   = (const float*)d_in[24];
  const float* bwhh   = (const float*)d_in[25];
  const float* bbhh   = (const float*)d_in[26];
  const float* blnihg = (const float*)d_in[27];
  const float* blnihb = (const float*)d_in[28];
  const float* blnhhg = (const float*)d_in[29];
  const float* blnhhb = (const float*)d_in[30];
  const float* blnhog = (const float*)d_in[31];
  const float* blnhob = (const float*)d_in[32];
  const float* attnw  = (const float*)d_in[33];
  const float* fc1w   = (const float*)d_in[34];
  const float* fc1b   = (const float*)d_in[35];
  const float* bn3g   = (const float*)d_in[36];
  const float* bn3b   = (const float*)d_in[37];
  const float* bn3m   = (const float*)d_in[38];
  const float* bn3v   = (const float*)d_in[39];
  const float* fc2w   = (const float*)d_in[40];
  const float* fc2b_  = (const float*)d_in[41];

  // Workspace layout (<=128 MiB), liveness-based overlays:
  //   c1o  @   0 .. 32M   (conv1 out; dead after k_c2xp phase A)
  //   xpf  @  32M .. 80M
  //   xpb  @  80M ..128M
  //   hcat @   0 .. 24M   (lstm out; overlays dead c1o)
  //   (seq is never materialized — fused into k_c2xp LDS)
  char* ws = (char*)d_ws;
  const size_t MB = 1048576;
  u16* c1o  = (u16*)(ws);
  u16* xpf  = (u16*)(ws + 32*MB);
  u16* xpb  = (u16*)(ws + 80*MB);
  u16* hcat = (u16*)(ws);

  k_conv1<<<dim3(8,128),  256, 0, stream>>>(X, c1w, c1b, bn1g, bn1b, bn1m, bn1v, c1o);
  k_c2xp <<<dim3(4,128),  512, 0, stream>>>(c1o, c2w, c2b, bn2g, bn2b, bn2m, bn2v,
      fwih, fbih, flnihg, flnihb, bwih, bbih, blnihg, blnihb, xpf, xpb);
  k_lstm <<<dim3(128,2),  384, 0, stream>>>(xpf, xpb,
      fwhh, fbhh, flnhhg, flnhhb, flnhog, flnhob,
      bwhh, bbhh, blnhhg, blnhhb, blnhog, blnhob, hcat);
  k_head <<<dim3(128),    256, 0, stream>>>(hcat, attnw, fc1w, fc1b,
      bn3g, bn3b, bn3m, bn3v, fc2w, fc2b_, (float*)d_out);
}

// Round 11
// 1543.041 us; speedup vs baseline: 1.0563x; 1.0563x over previous
//
#include <hip/hip_runtime.h>

typedef unsigned short u16;
typedef unsigned int   u32;
typedef __attribute__((ext_vector_type(8))) short bf16x8;
typedef __attribute__((ext_vector_type(4))) float f32x4;

#define DI __device__ __forceinline__

DI float b2f(u16 u){ union{u32 i; float f;} x; x.i = ((u32)u)<<16; return x.f; }
DI u16 f2bf(float f){ union{float f; u32 i;} x; x.f=f; u32 r = x.i + 0x7FFFu + ((x.i>>16)&1u); return (u16)(r>>16); }
DI float sigf(float x){ return 1.0f/(1.0f + __expf(-x)); }
DI float tanh_(float x){ return 1.0f - 2.0f/(__expf(2.0f*x)+1.0f); }
DI float dot4(float4 a, float4 b){ return a.x*b.x + a.y*b.y + a.z*b.z + a.w*b.w; }

// ---------------- conv1 (k=7,pad3) + BN1 + ReLU + maxpool2 ----------------
// x: [128][2048][8] f32  -> out: [128][128][1024] bf16  (layout [b][co][t'])
// Register-blocked: thread owns pooled pair (2*p2, 2*p2+1); its 20 x-float4s
// loaded ONCE (xs pitch 12 floats -> conflict-free); W reads wave-uniform.
__global__ __launch_bounds__(256) void k_conv1(
    const float* __restrict__ x, const float* __restrict__ w,
    const float* __restrict__ cb, const float* __restrict__ bg, const float* __restrict__ bb,
    const float* __restrict__ bm, const float* __restrict__ bv, u16* __restrict__ out)
{
  __shared__ __align__(16) float xs[262*12];    // [tau+3][8ci pad12]
  __shared__ __align__(16) float wl[128*7*8];   // [co][k][ci]
  __shared__ float As[128], Ss[128];
  const int tid = threadIdx.x;
  const int tc  = blockIdx.x;       // 8 chunks of 128 pooled positions
  const int b   = blockIdx.y;
  const int tau0 = tc*256;
  for(int f = tid; f < 262*8; f += 256){
    int tt = f >> 3;
    int ci = f & 7;
    int xg = tau0 - 3 + tt;
    float val = 0.f;
    if(xg >= 0 && xg < 2048) val = x[(b*2048 + xg)*8 + ci];
    xs[tt*12 + ci] = val;
  }
  for(int d = tid; d < 128*7*8; d += 256){
    int co = d / 56; int r = d - co*56; int k = r >> 3; int ci = r & 7;
    wl[d] = w[(co*8 + ci)*7 + k];
  }
  if(tid < 128){
    float a = bg[tid] * rsqrtf(bv[tid] + 1e-5f);
    As[tid] = a;
    Ss[tid] = (cb[tid] - bm[tid])*a + bb[tid];
  }
  __syncthreads();
  const float4* xs4 = (const float4*)xs;
  const float4* wl4 = (const float4*)wl;
  const int p2  = tid & 63;         // pooled pair index (p = 2*p2, 2*p2+1)
  const int grp = tid >> 6;         // co group (wave-uniform)
  float4 ra[10], rb[10];
  #pragma unroll
  for(int e=0; e<10; e++){ ra[e] = xs4[(4*p2+e)*3]; rb[e] = xs4[(4*p2+e)*3 + 1]; }
  u32* out32 = (u32*)out;
  for(int i = 0; i < 32; i++){
    const int co = grp*32 + i;
    float a0=0.f, a1=0.f, a2=0.f, a3=0.f;
    #pragma unroll
    for(int k=0;k<7;k++){
      float4 wa = wl4[(co*7+k)*2], wb2 = wl4[(co*7+k)*2+1];
      a0 += dot4(ra[k],   wa) + dot4(rb[k],   wb2);
      a1 += dot4(ra[k+1], wa) + dot4(rb[k+1], wb2);
      a2 += dot4(ra[k+2], wa) + dot4(rb[k+2], wb2);
      a3 += dot4(ra[k+3], wa) + dot4(rb[k+3], wb2);
    }
    const float Ac = As[co], Sc = Ss[co];
    const float y0 = fmaxf(fmaxf(a0*Ac+Sc, a1*Ac+Sc), 0.f);
    const float y1 = fmaxf(fmaxf(a2*Ac+Sc, a3*Ac+Sc), 0.f);
    out32[((b*128 + co)<<9) + tc*64 + p2] = (u32)f2bf(y0) | ((u32)f2bf(y1) << 16);
  }
}

// ---------------- W2 3-way bf16 split prep ----------------
// w: [256][128][5] f32 -> wp3: [3][5][4][256][40] bf16 (pitch 40 kills bank
// conflicts on conv2's B-fragment reads). hi+lo1+lo2 recovers all 24 mantissa
// bits of f32 W -> conv2 products exact, == f32 conv up to add ordering.
__global__ __launch_bounds__(256) void k_prep(
    const float* __restrict__ w, u16* __restrict__ wp3)
{
  const int f = blockIdx.x*256 + threadIdx.x;   // 0..163839
  const int co = f / 640; const int r = f - co*640;
  const int ci = r / 5;   const int k = r - ci*5;
  const float wv = w[f];
  const u16 h0 = f2bf(wv);
  const float r1 = wv - b2f(h0);                // exact in f32
  const u16 h1 = f2bf(r1);
  const float r2 = r1 - b2f(h1);                // exact in f32
  const u16 h2 = f2bf(r2);
  const int cib = ci >> 5, cl = ci & 31;
  const int base = (k*4 + cib)*10240 + co*40 + cl;
  wp3[base]                = h0;
  wp3[base +   5*4*10240]  = h1;
  wp3[base + 2*5*4*10240]  = h2;
}

// ---------------- conv2 via 3-way-split bf16 MFMA (4 tau-tiles/wave) -------
// in: [128][128][1024] bf16 -> seq: [512][128][256] bf16 (layout [t'][b][co])
// Block covers 256 tau x 256 co; each wave owns 4 tau-tiles and one co-half.
// B-fragments read once per K-step, reused 4x; W staged as pure uint4 copies
// from precomputed wp3.
__global__ __launch_bounds__(512) void k_conv2(
    const u16* __restrict__ cin, const u16* __restrict__ wp3,
    const float* __restrict__ cb, const float* __restrict__ bg, const float* __restrict__ bb,
    const float* __restrict__ bm, const float* __restrict__ bv, u16* __restrict__ seq)
{
  __shared__ __align__(16) u16 xsT[260*136];   // [tt][ci], tt = tau_local+2
  __shared__ __align__(16) u16 wb[3][256*40];  // W splits [co][cl(32) pad40]
  __shared__ float As[256], Ss[256];
  const int tid = threadIdx.x;
  const int tc  = blockIdx.x;    // 0..3 (256 tau each)
  const int b   = blockIdx.y;
  const int wav = tid >> 6;
  const int rt  = wav & 3;       // base tau-tile
  const int coh = wav >> 2;      // co half (128)
  const int l = tid & 63;
  const int g = l >> 4;          // k-group 0..3
  const int c = l & 15;
  if(tid < 256){
    float a = bg[tid] * rsqrtf(bv[tid] + 1e-5f);
    As[tid] = a; Ss[tid] = (cb[tid] - bm[tid])*a + bb[tid];
  }
  // stage X^T: tt = 0..259 <-> tg = tc*256 - 2 + tt
  for(int f = tid; f < 33280; f += 512){
    int ci = f / 260, tt = f - ci*260;
    int tg = tc*256 - 2 + tt;
    u16 val = 0;
    if(tg >= 0 && tg < 1024) val = cin[((b*128 + ci)<<10) + tg];
    xsT[tt*136 + ci] = val;
  }
  f32x4 acc[4][8];
  #pragma unroll
  for(int q4=0;q4<4;q4++)
    #pragma unroll
    for(int n=0;n<8;n++) acc[q4][n] = (f32x4){0.f,0.f,0.f,0.f};
  for(int s=0; s<20; s++){
    const int k = s >> 2, cib = s & 3;
    __syncthreads();                 // prev MFMA reads done; (iter0: xsT/As ready)
    #pragma unroll
    for(int sp=0; sp<3; sp++){
      const uint4* src = (const uint4*)(wp3 + ((sp*5 + k)*4 + cib)*10240);
      uint4* dst = (uint4*)wb[sp];
      for(int f = tid; f < 1280; f += 512) dst[f] = src[f];
    }
    __syncthreads();                 // wb visible
    bf16x8 afr[4];
    #pragma unroll
    for(int q4=0;q4<4;q4++)
      afr[q4] = *(const bf16x8*)&xsT[((q4*4 + rt)*16 + c + k)*136 + cib*32 + g*8];
    #pragma unroll
    for(int n=0; n<8; n++){
      bf16x8 b0 = *(const bf16x8*)&wb[0][(coh*128 + n*16 + c)*40 + g*8];
      bf16x8 b1 = *(const bf16x8*)&wb[1][(coh*128 + n*16 + c)*40 + g*8];
      bf16x8 b2 = *(const bf16x8*)&wb[2][(coh*128 + n*16 + c)*40 + g*8];
      #pragma unroll
      for(int q4=0;q4<4;q4++){
        acc[q4][n] = __builtin_amdgcn_mfma_f32_16x16x32_bf16(afr[q4], b0, acc[q4][n], 0, 0, 0);
        acc[q4][n] = __builtin_amdgcn_mfma_f32_16x16x32_bf16(afr[q4], b1, acc[q4][n], 0, 0, 0);
        acc[q4][n] = __builtin_amdgcn_mfma_f32_16x16x32_bf16(afr[q4], b2, acc[q4][n], 0, 0, 0);
      }
    }
  }
  // epilogue: BN + ReLU + maxpool2; tau = tc*256 + T*16 + g*4 + q
  #pragma unroll
  for(int q4=0;q4<4;q4++){
    const int T = q4*4 + rt;
    const int tp0 = tc*128 + T*8 + g*2;
    #pragma unroll
    for(int n=0; n<8; n++){
      int co = coh*128 + n*16 + c;
      float Ac = As[co], Sc = Ss[co];
      float p0 = fmaxf(fmaxf(acc[q4][n][0]*Ac+Sc, acc[q4][n][1]*Ac+Sc), 0.f);
      float p1 = fmaxf(fmaxf(acc[q4][n][2]*Ac+Sc, acc[q4][n][3]*Ac+Sc), 0.f);
      seq[((tp0+0)*128 + b)*256 + co] = f2bf(p0);
      seq[((tp0+1)*128 + b)*256 + co] = f2bf(p1);
    }
  }
}

// ---------------- xp = LN(seq @ wih.T + bih)  via split-precision bf16 MFMA --
__global__ __launch_bounds__(512) void k_xp(
    const u16* __restrict__ seq,
    const float* __restrict__ fw, const float* __restrict__ fbi, const float* __restrict__ fg, const float* __restrict__ fb,
    const float* __restrict__ bw, const float* __restrict__ bbi, const float* __restrict__ bg_, const float* __restrict__ bb_,
    u16* __restrict__ xpf, u16* __restrict__ xpb)
{
  __shared__ __align__(16) char lds[104960];
  u16*   wbh  = (u16*)lds;                       // W_hi [384][40] bf16
  u16*   wbl  = (u16*)(lds + 30720);             // W_lo [384][40] bf16
  u16*   ost  = (u16*)lds;                       // outstage [128][392] bf16
  float* lnbi = (float*)(lds + 100352);
  float* lng  = lnbi + 384;
  float* lnb2 = lnbi + 768;
  const float *W, *BI, *LG, *LB; u16* out;
  if(blockIdx.y == 0){ W=fw; BI=fbi; LG=fg;  LB=fb;  out=xpf; }
  else               { W=bw; BI=bbi; LG=bg_; LB=bb_; out=xpb; }
  const int tid = threadIdx.x;
  const int row0 = blockIdx.x * 128;
  const int w = tid >> 6;        // wave -> 16-row tile
  const int l = tid & 63;
  const int g = l >> 4;          // k-group 0..3
  const int c = l & 15;          // col-within-tile / row-within-tile
  if(tid < 384){ lnbi[tid] = BI[tid]; lng[tid] = LG[tid]; lnb2[tid] = LB[tid]; }
  const int arow = row0 + w*16 + c;
  bf16x8 afr[8];
  #pragma unroll
  for(int ks=0; ks<8; ks++)
    afr[ks] = *(const bf16x8*)&seq[arow*256 + ks*32 + g*8];
  f32x4 acc[24];
  #pragma unroll
  for(int n=0; n<24; n++) acc[n] = (f32x4){0.f,0.f,0.f,0.f};
  #pragma unroll
  for(int ks=0; ks<8; ks++){
    __syncthreads();
    for(int f = tid; f < 12288; f += 512){
      int jj = f >> 5, kk = f & 31;
      float wv = W[jj*256 + ks*32 + kk];
      u16 hi = f2bf(wv);
      wbh[jj*40 + kk] = hi;
      wbl[jj*40 + kk] = f2bf(wv - b2f(hi));
    }
    __syncthreads();
    #pragma unroll
    for(int n=0; n<24; n++){
      bf16x8 bhi = *(const bf16x8*)&wbh[(n*16 + c)*40 + g*8];
      bf16x8 blo = *(const bf16x8*)&wbl[(n*16 + c)*40 + g*8];
      acc[n] = __builtin_amdgcn_mfma_f32_16x16x32_bf16(afr[ks], bhi, acc[n], 0, 0, 0);
      acc[n] = __builtin_amdgcn_mfma_f32_16x16x32_bf16(afr[ks], blo, acc[n], 0, 0, 0);
    }
  }
  __syncthreads();
  float bic[24];
  #pragma unroll
  for(int n=0; n<24; n++) bic[n] = lnbi[n*16 + c];
  float mean[4], rs[4];
  #pragma unroll
  for(int q=0; q<4; q++){
    float s = 0.f, ss = 0.f;
    #pragma unroll
    for(int n=0; n<24; n++){
      float u = acc[n][q] + bic[n];
      s += u; ss += u*u;
    }
    #pragma unroll
    for(int msk=1; msk<16; msk<<=1){ s += __shfl_xor(s,msk); ss += __shfl_xor(ss,msk); }
    mean[q] = s * (1.f/384.f);
    float var = fmaxf(ss * (1.f/384.f) - mean[q]*mean[q], 0.f);
    rs[q] = rsqrtf(var + 1e-5f);
  }
  #pragma unroll
  for(int n=0; n<24; n++){
    float lgv = lng[n*16 + c], lbv = lnb2[n*16 + c];
    #pragma unroll
    for(int q=0; q<4; q++){
      float u = acc[n][q] + bic[n];
      float y = (u - mean[q])*rs[q]*lgv + lbv;
      ost[(w*16 + g*4 + q)*392 + n*16 + c] = f2bf(y);
    }
  }
  __syncthreads();
  for(int f = tid; f < 6144; f += 512){
    int row = f / 48, ch = f - row*48;
    uint4 v = *(const uint4*)&ost[row*392 + ch*8];
    *(uint4*)&out[(row0 + row)*384 + ch*8] = v;
  }
}

// ---------------- LayerNorm-LSTM scan (one block per (batch,dir)) ----------------
// R0 structure (validated local optimum across 6 restructure attempts) +
// batched hcat stores + xt prefetch (neutral but harmless).
__global__ __launch_bounds__(384) void k_lstm(
    const u16* __restrict__ xpf, const u16* __restrict__ xpb,
    const float* __restrict__ fwhh, const float* __restrict__ fbhh, const float* __restrict__ fgh, const float* __restrict__ fbh2,
    const float* __restrict__ fgho, const float* __restrict__ fbho,
    const float* __restrict__ bwhh, const float* __restrict__ bbhh, const float* __restrict__ bgh, const float* __restrict__ bbh2,
    const float* __restrict__ bgho, const float* __restrict__ bbho,
    u16* __restrict__ hcat)
{
  __shared__ float4 hx4[24];
  __shared__ float gbuf[384];
  __shared__ float red[16];
  __shared__ __align__(16) u16 hstage[8][96];   // 8 steps of hy
  const int b   = blockIdx.x;
  const int dir = blockIdx.y;
  const u16* xp;
  const float *whh, *bh, *gh, *bh2, *gho, *bho;
  if(dir == 0){ xp=xpf; whh=fwhh; bh=fbhh; gh=fgh; bh2=fbh2; gho=fgho; bho=fbho; }
  else        { xp=xpb; whh=bwhh; bh=bbhh; gh=bgh; bh2=bbh2; gho=bgho; bho=bbho; }
  const int j = threadIdx.x;
  const int wid = j >> 6;
  float wr[96];                         // whh row j in registers
  {
    const float4* wp4 = (const float4*)(whh + j*96);
    #pragma unroll
    for(int kk=0; kk<24; kk++){
      float4 v = wp4[kk];
      wr[4*kk]=v.x; wr[4*kk+1]=v.y; wr[4*kk+2]=v.z; wr[4*kk+3]=v.w;
    }
  }
  const float bh_j = bh[j], gh_j = gh[j], bh2_j = bh2[j];
  float gho_j = 0.f, bho_j = 0.f, cx = 0.f;
  if(j < 96){ gho_j = gho[j]; bho_j = bho[j]; }
  float* hx = (float*)hx4;
  if(j < 96) hx[j] = 0.f;
  const u16* xrow = xp + b*384 + j;      // + ts*49152 per step
  u16 xt_u = xrow[(dir ? 511 : 0)*49152];
  __syncthreads();
  for(int t=0; t<512; t++){
    const int ts = dir ? (511 - t) : t;
    u16 xn = 0;
    if(t < 511) xn = xrow[(dir ? (510 - t) : (t + 1))*49152];
    const float xt = b2f(xt_u);
    float a0=0.f,a1=0.f,a2=0.f,a3=0.f;
    #pragma unroll
    for(int kk=0; kk<24; kk++){
      float4 h4 = hx4[kk];              // broadcast read
      a0 += h4.x * wr[4*kk];
      a1 += h4.y * wr[4*kk+1];
      a2 += h4.z * wr[4*kk+2];
      a3 += h4.w * wr[4*kk+3];
    }
    const float u = (a0+a1)+(a2+a3) + bh_j;
    float s = u, ss = u*u;
    #pragma unroll
    for(int msk=32; msk; msk>>=1){ s += __shfl_xor(s,msk); ss += __shfl_xor(ss,msk); }
    if((j & 63) == 0){ red[wid*2] = s; red[wid*2+1] = ss; }
    __syncthreads();
    float S=0.f, SS=0.f;
    #pragma unroll
    for(int wv=0; wv<6; wv++){ S += red[wv*2]; SS += red[wv*2+1]; }
    const float mean = S*(1.f/384.f);
    const float var  = fmaxf(SS*(1.f/384.f) - mean*mean, 0.f);
    const float rs   = rsqrtf(var + 1e-5f);
    const float gate = xt + (u - mean)*rs*gh_j + bh2_j;
    gbuf[j] = gate;
    __syncthreads();
    float cy = 0.f, go_ = 0.f;
    if(j < 128){
      if(j < 96){
        float gi = gbuf[j], gf = gbuf[j+96], gg = gbuf[j+192];
        go_ = gbuf[j+288];
        cy = sigf(gf)*cx + sigf(gi)*tanh_(gg);
        cx = cy;
      }
      float s2 = cy, ss2 = cy*cy;
      #pragma unroll
      for(int msk=32; msk; msk>>=1){ s2 += __shfl_xor(s2,msk); ss2 += __shfl_xor(ss2,msk); }
      if((j & 63) == 0){ red[12 + wid*2] = s2; red[13 + wid*2] = ss2; }
    }
    __syncthreads();
    if(j < 96){
      const float S2 = red[12]+red[14], SS2 = red[13]+red[15];
      const float m2  = S2*(1.f/96.f);
      const float v2  = fmaxf(SS2*(1.f/96.f) - m2*m2, 0.f);
      const float rs2 = rsqrtf(v2 + 1e-5f);
      const float lnho = (cy - m2)*rs2*gho_j + bho_j;
      const float hy = sigf(go_)*tanh_(lnho);
      hx[j] = hy;
      hstage[t & 7][j] = f2bf(hy);
    }
    xt_u = xn;
    __syncthreads();
    if((t & 7) == 7){
      if(j < 96){
        const int row = j / 12, ch = j - row*12;
        const int tt = (t - 7) + row;
        const int tsr = dir ? (511 - tt) : tt;
        uint4 v = *(const uint4*)&hstage[row][ch*8];
        *(uint4*)&hcat[(tsr*128 + b)*192 + dir*96 + ch*8] = v;
      }
    }
  }
}

// ---------------- attention + fc1/BN3/ReLU + fc2 (one block per batch) ----------------
__global__ __launch_bounds__(256) void k_head(
    const u16* __restrict__ hcat, const float* __restrict__ aw,
    const float* __restrict__ f1w, const float* __restrict__ f1b,
    const float* __restrict__ g3, const float* __restrict__ b3, const float* __restrict__ m3, const float* __restrict__ v3,
    const float* __restrict__ fc2w, const float* __restrict__ fc2bias,
    float* __restrict__ out)
{
  __shared__ float p[512];
  __shared__ float red[8];
  __shared__ __align__(16) float ctx[192];
  __shared__ float h2[256];
  __shared__ float awl[192];
  const int b = blockIdx.x;
  const int tid = threadIdx.x;
  if(tid < 192) awl[tid] = aw[tid];
  __syncthreads();
  float sc0 = 0.f, sc1 = 0.f;
  #pragma unroll
  for(int i=0;i<2;i++){
    int t = i*256 + tid;
    const uint4* hp = (const uint4*)(hcat + (t*128 + b)*192);
    float acc = 0.f;
    #pragma unroll 6
    for(int qq=0;qq<24;qq++){
      uint4 pv = hp[qq];
      acc += b2f((u16)(pv.x&0xffffu))*awl[qq*8+0] + b2f((u16)(pv.x>>16))*awl[qq*8+1]
           + b2f((u16)(pv.y&0xffffu))*awl[qq*8+2] + b2f((u16)(pv.y>>16))*awl[qq*8+3]
           + b2f((u16)(pv.z&0xffffu))*awl[qq*8+4] + b2f((u16)(pv.z>>16))*awl[qq*8+5]
           + b2f((u16)(pv.w&0xffffu))*awl[qq*8+6] + b2f((u16)(pv.w>>16))*awl[qq*8+7];
    }
    if(i==0) sc0 = acc; else sc1 = acc;
  }
  float mx = fmaxf(sc0, sc1);
  for(int msk=32; msk; msk>>=1) mx = fmaxf(mx, __shfl_xor(mx,msk));
  if((tid&63)==0) red[tid>>6] = mx;
  __syncthreads();
  mx = fmaxf(fmaxf(red[0],red[1]), fmaxf(red[2],red[3]));
  float e0 = __expf(sc0-mx), e1 = __expf(sc1-mx);
  float sm = e0 + e1;
  for(int msk=32; msk; msk>>=1) sm += __shfl_xor(sm,msk);
  if((tid&63)==0) red[4 + (tid>>6)] = sm;
  __syncthreads();
  const float inv = 1.f/(red[4]+red[5]+red[6]+red[7]);
  p[tid] = e0*inv; p[tid+256] = e1*inv;
  __syncthreads();
  if(tid < 192){
    float acc = 0.f;
    for(int t=0;t<512;t++){
      acc += p[t] * b2f(hcat[(t*128 + b)*192 + tid]);
    }
    ctx[tid] = acc;
  }
  __syncthreads();
  {
    const float4* cv = (const float4*)ctx;
    const float4* wp = (const float4*)(f1w + tid*192);
    float acc = 0.f;
    #pragma unroll 8
    for(int qq=0;qq<48;qq++){
      acc += dot4(wp[qq], cv[qq]);
    }
    acc += f1b[tid];
    float a = g3[tid] * rsqrtf(v3[tid] + 1e-5f);
    float y = (acc - m3[tid])*a + b3[tid];
    h2[tid] = fmaxf(y, 0.f);
  }
  __syncthreads();
  if(tid < 6){
    float acc = fc2bias[tid];
    for(int k=0;k<256;k++) acc += h2[k]*fc2w[tid*256 + k];
    out[b*6 + tid] = acc;
  }
}

extern "C" void kernel_launch(void* const* d_in, const int* in_sizes, int n_in,
                              void* d_out, int out_size, void* d_ws, size_t ws_size,
                              hipStream_t stream)
{
  (void)in_sizes; (void)n_in; (void)out_size; (void)ws_size;
  const float* X      = (const float*)d_in[0];
  const float* c1w    = (const float*)d_in[1];
  const float* c1b    = (const float*)d_in[2];
  const float* bn1g   = (const float*)d_in[3];
  const float* bn1b   = (const float*)d_in[4];
  const float* bn1m   = (const float*)d_in[5];
  const float* bn1v   = (const float*)d_in[6];
  const float* c2w    = (const float*)d_in[7];
  const float* c2b    = (const float*)d_in[8];
  const float* bn2g   = (const float*)d_in[9];
  const float* bn2b   = (const float*)d_in[10];
  const float* bn2m   = (const float*)d_in[11];
  const float* bn2v   = (const float*)d_in[12];
  const float* fwih   = (const float*)d_in[13];
  const float* fbih   = (const float*)d_in[14];
  const float* fwhh   = (const float*)d_in[15];
  const float* fbhh   = (const float*)d_in[16];
  const float* flnihg = (const float*)d_in[17];
  const float* flnihb = (const float*)d_in[18];
  const float* flnhhg = (const float*)d_in[19];
  const float* flnhhb = (const float*)d_in[20];
  const float* flnhog = (const float*)d_in[21];
  const float* flnhob = (const float*)d_in[22];
  const float* bwih   = (const float*)d_in[23];
  const float* bbih   = (const float*)d_in[24];
  const float* bwhh   = (const float*)d_in[25];
  const float* bbhh   = (const float*)d_in[26];
  const float* blnihg = (const float*)d_in[27];
  const float* blnihb = (const float*)d_in[28];
  const float* blnhhg = (const float*)d_in[29];
  const float* blnhhb = (const float*)d_in[30];
  const float* blnhog = (const float*)d_in[31];
  const float* blnhob = (const float*)d_in[32];
  const float* attnw  = (const float*)d_in[33];
  const float* fc1w   = (const float*)d_in[34];
  const float* fc1b   = (const float*)d_in[35];
  const float* bn3g   = (const float*)d_in[36];
  const float* bn3b   = (const float*)d_in[37];
  const float* bn3m   = (const float*)d_in[38];
  const float* bn3v   = (const float*)d_in[39];
  const float* fc2w   = (const float*)d_in[40];
  const float* fc2b_  = (const float*)d_in[41];

  // Workspace layout (peak 128 MiB), liveness-based overlays:
  //   seq   @   0 .. 32M   (conv2 out; dead after k_xp)
  //   xpf   @  32M .. 80M
  //   xpb   @  80M ..128M  (written by k_xp, AFTER conv2)
  //   wprep @  80M .. 81.2M (k_prep out; read only by conv2 -> overlays xpb)
  //   c1o   @  96M ..128M  (conv1 out; dead after conv2)
  //   hcat  @   0 .. 24M   (lstm out; overlays dead seq)
  char* ws = (char*)d_ws;
  const size_t MB = 1048576;
  u16* seq   = (u16*)(ws);
  u16* xpf   = (u16*)(ws + 32*MB);
  u16* xpb   = (u16*)(ws + 80*MB);
  u16* wprep = (u16*)(ws + 80*MB);
  u16* c1o   = (u16*)(ws + 96*MB);
  u16* hcat  = (u16*)(ws);

  k_prep <<<dim3(640),    256, 0, stream>>>(c2w, wprep);
  k_conv1<<<dim3(8,128),  256, 0, stream>>>(X,   c1w, c1b, bn1g, bn1b, bn1m, bn1v, c1o);
  k_conv2<<<dim3(4,128),  512, 0, stream>>>(c1o, wprep, c2b, bn2g, bn2b, bn2m, bn2v, seq);
  k_xp  <<<dim3(512,2),   512, 0, stream>>>(seq, fwih, fbih, flnihg, flnihb,
                                                 bwih, bbih, blnihg, blnihb, xpf, xpb);
  k_lstm<<<dim3(128,2),   384, 0, stream>>>(xpf, xpb,
      fwhh, fbhh, flnhhg, flnhhb, flnhog, flnhob,
      bwhh, bbhh, blnhhg, blnhhb, blnhog, blnhob, hcat);
  k_head<<<dim3(128),     256, 0, stream>>>(hcat, attnw, fc1w, fc1b,
      bn3g, bn3b, bn3m, bn3v, fc2w, fc2b_, (float*)d_out);
}